// Round 1
// baseline (10407.812 us; speedup 1.0000x reference)
//
#include <hip/hip_runtime.h>

// CGIterator: N=50000 nodes, K=128, I=4 chained CG iterations, fp32.
// Fully fused: one block = 4 nodes through all 4 iterations.
// feats live in registers (thread owns (node,k), all 9 m);
// channel-mixing steps go through LDS (thread owns column p).
//
// This revision targets the L2-latency stalls on weight loads:
//  - l-fused K-steps of 8: 288 FMAs per 24-load batch (was 16..80 per 4-load)
//  - explicit double-buffered weight prefetch (one step ahead)
//  - linear_out p-split: each half-warp-group sums 128 p's for ALL 4 nodes
//    (halves W_out loads; W_out read once per block, was twice), then a
//    conflict-free 18-float LDS exchange (aliased onto dead s_h).

#define NNODES 50000
#define KCH 128          // K
#define PCH 256          // 2K
#define NITER 4
#define NB 4             // nodes per block

// ---- linear_in helpers: acc[NB][9] over s_h, weights buf[3][8] ----
#define LOADWIN(buf, kb) do { \
    _Pragma("unroll") \
    for (int r = 0; r < 8; ++r) { \
        buf[0][r] = W0[((kb) + r) * PCH]; \
        buf[1][r] = W1[((kb) + r) * PCH]; \
        buf[2][r] = W2[((kb) + r) * PCH]; \
    } \
} while (0)

#define INSTEP(buf, kb) do { \
    _Pragma("unroll") \
    for (int n = 0; n < NB; ++n) { \
        _Pragma("unroll") \
        for (int m = 0; m < 9; ++m) { \
            const int lm = (m == 0) ? 0 : ((m < 4) ? 1 : 2); \
            const float4 hA = *(const float4*)&s_h[n][m][(kb)]; \
            const float4 hB = *(const float4*)&s_h[n][m][(kb) + 4]; \
            float a = acc[n][m]; \
            a = fmaf(hA.x, buf[lm][0], a); \
            a = fmaf(hA.y, buf[lm][1], a); \
            a = fmaf(hA.z, buf[lm][2], a); \
            a = fmaf(hA.w, buf[lm][3], a); \
            a = fmaf(hB.x, buf[lm][4], a); \
            a = fmaf(hB.y, buf[lm][5], a); \
            a = fmaf(hB.z, buf[lm][6], a); \
            a = fmaf(hB.w, buf[lm][7], a); \
            acc[n][m] = a; \
        } \
    } \
} while (0)

// ---- linear_out helpers: acc[NB][9] over s_hc (own p-half), weights buf[3][8] ----
#define LOADWOUT(buf, pb) do { \
    _Pragma("unroll") \
    for (int r = 0; r < 8; ++r) { \
        buf[0][r] = V0[(size_t)(pb0 + (pb) + r) * KCH]; \
        buf[1][r] = V1[(size_t)(pb0 + (pb) + r) * KCH]; \
        buf[2][r] = V2[(size_t)(pb0 + (pb) + r) * KCH]; \
    } \
} while (0)

#define OUTSTEP(buf, pb) do { \
    _Pragma("unroll") \
    for (int n = 0; n < NB; ++n) { \
        _Pragma("unroll") \
        for (int m = 0; m < 9; ++m) { \
            const int lm = (m == 0) ? 0 : ((m < 4) ? 1 : 2); \
            const float4 tA = *(const float4*)&s_hc[n][m][pb0 + (pb)]; \
            const float4 tB = *(const float4*)&s_hc[n][m][pb0 + (pb) + 4]; \
            float a = acc[n][m]; \
            a = fmaf(tA.x, buf[lm][0], a); \
            a = fmaf(tA.y, buf[lm][1], a); \
            a = fmaf(tA.z, buf[lm][2], a); \
            a = fmaf(tA.w, buf[lm][3], a); \
            a = fmaf(tB.x, buf[lm][4], a); \
            a = fmaf(tB.y, buf[lm][5], a); \
            a = fmaf(tB.z, buf[lm][6], a); \
            a = fmaf(tB.w, buf[lm][7], a); \
            acc[n][m] = a; \
        } \
    } \
} while (0)

__global__ __launch_bounds__(256, 2)
void cg_fused(const float* __restrict__ f0,
              const float* __restrict__ f1,
              const float* __restrict__ f2,
              const float* __restrict__ Uin,
              const float* __restrict__ gamma,
              const float* __restrict__ W_in,
              const float* __restrict__ W_out,
              float* __restrict__ out)
{
    // symmetrized U, upper triangle a<=b packed: sUp[ab][c], c padded to 12 for b128
    __shared__ float sUp[45][12];
    __shared__ float s_h[NB][9][KCH];    // RMS-normed feats; dead after linear_in,
                                         // reused as the linear_out exchange buffer
    __shared__ float s_hc[NB][9][PCH];   // hc, overwritten in place by tp

    // exchange view: s_red[half][j=node2*9+m][kk], 2*18*128*4B == sizeof(s_h)
    float (*s_red)[18][KCH] = reinterpret_cast<float (*)[18][KCH]>(&s_h[0][0][0]);

    const int tid = threadIdx.x;
    const int node0 = blockIdx.x * NB;

    // ---- build symmetrized padded U in LDS (once per block)
    for (int idx = tid; idx < 45 * 12; idx += 256) {
        const int ab = idx / 12;
        const int c  = idx % 12;
        int a = 0, r = ab;
        while (r >= 9 - a) { r -= 9 - a; ++a; }
        const int b = a + r;
        float v = 0.0f;
        if (c < 9) {
            v = Uin[(a * 9 + b) * 9 + c];
            if (a != b) v += Uin[(b * 9 + a) * 9 + c];
        }
        sUp[ab][c] = v;
    }

    const int kk = tid & (KCH - 1);  // channel 0..127
    const int nh = tid >> 7;         // node-half: 0 or 1 (wave-uniform)
    const int p  = tid;              // expanded channel column 0..255

    // ---- load initial feats: thread owns nodes 2*nh+{0,1}, channel kk, all m
    float f[2][9];
    #pragma unroll
    for (int j = 0; j < 2; ++j) {
        const int n = node0 + 2 * nh + j;
        f[j][0] = f0[n * KCH + kk];
        #pragma unroll
        for (int m = 0; m < 3; ++m) f[j][1 + m] = f1[(n * 3 + m) * KCH + kk];
        #pragma unroll
        for (int m = 0; m < 5; ++m) f[j][4 + m] = f2[(n * 5 + m) * KCH + kk];
    }

    for (int it = 0; it < NITER; ++it) {
        // ---------- step 1: equivariant RMS norm -> s_h ----------
        const float g0 = gamma[(it * 3 + 0) * KCH + kk];
        const float g1 = gamma[(it * 3 + 1) * KCH + kk];
        const float g2 = gamma[(it * 3 + 2) * KCH + kk];
        #pragma unroll
        for (int j = 0; j < 2; ++j) {
            const int nl = 2 * nh + j;
            const float s0 = f[j][0] * f[j][0];
            const float s1 = f[j][1] * f[j][1] + f[j][2] * f[j][2] + f[j][3] * f[j][3];
            const float s2 = f[j][4] * f[j][4] + f[j][5] * f[j][5] + f[j][6] * f[j][6]
                           + f[j][7] * f[j][7] + f[j][8] * f[j][8];
            const float r0 = rsqrtf(s0 + 1e-6f) * g0;
            const float r1 = rsqrtf(s1 * (1.0f / 3.0f) + 1e-6f) * g1;
            const float r2 = rsqrtf(s2 * (1.0f / 5.0f) + 1e-6f) * g2;
            s_h[nl][0][kk] = f[j][0] * r0;
            s_h[nl][1][kk] = f[j][1] * r1;
            s_h[nl][2][kk] = f[j][2] * r1;
            s_h[nl][3][kk] = f[j][3] * r1;
            s_h[nl][4][kk] = f[j][4] * r2;
            s_h[nl][5][kk] = f[j][5] * r2;
            s_h[nl][6][kk] = f[j][6] * r2;
            s_h[nl][7][kk] = f[j][7] * r2;
            s_h[nl][8][kk] = f[j][8] * r2;
        }
        __syncthreads();   // s_h visible to all (also orders sUp build on it==0)

        // ---------- step 2: linear_in, l-fused, K-step 8, double-buffered weights
        {
            const float* W0 = W_in + (size_t)(it * 3 + 0) * KCH * PCH + p;
            const float* W1 = W_in + (size_t)(it * 3 + 1) * KCH * PCH + p;
            const float* W2 = W_in + (size_t)(it * 3 + 2) * KCH * PCH + p;
            float acc[NB][9];
            #pragma unroll
            for (int n = 0; n < NB; ++n)
                #pragma unroll
                for (int m = 0; m < 9; ++m) acc[n][m] = 0.0f;

            float wa[3][8], wb[3][8];
            LOADWIN(wa, 0);
            #pragma unroll 1
            for (int kb = 0; kb < KCH - 16; kb += 16) {
                LOADWIN(wb, kb + 8);
                INSTEP(wa, kb);
                LOADWIN(wa, kb + 16);
                INSTEP(wb, kb + 8);
            }
            {   // tail: kb = 112
                LOADWIN(wb, 120);
                INSTEP(wa, 112);
                INSTEP(wb, 120);
            }
            #pragma unroll
            for (int n = 0; n < NB; ++n)
                #pragma unroll
                for (int m = 0; m < 9; ++m)
                    s_hc[n][m][p] = acc[n][m];
        }
        // no barrier: s_hc column p is written and read by the same thread

        // ---------- step 3: channel-wise CG tensor product (in place, own column p)
        {
            float v[NB][9];
            #pragma unroll
            for (int n = 0; n < NB; ++n)
                #pragma unroll
                for (int a = 0; a < 9; ++a) v[n][a] = s_hc[n][a][p];

            float acc[NB][9];
            #pragma unroll
            for (int n = 0; n < NB; ++n)
                #pragma unroll
                for (int c = 0; c < 9; ++c) acc[n][c] = 0.0f;

            int ab = 0;
            #pragma unroll
            for (int a = 0; a < 9; ++a) {
                #pragma unroll
                for (int b = a; b < 9; ++b) {
                    const float q0 = v[0][a] * v[0][b];
                    const float q1 = v[1][a] * v[1][b];
                    const float q2 = v[2][a] * v[2][b];
                    const float q3 = v[3][a] * v[3][b];
                    const float4 u0 = *(const float4*)&sUp[ab][0];
                    const float4 u1 = *(const float4*)&sUp[ab][4];
                    const float  u8 = sUp[ab][8];
                    const float uu[9] = {u0.x, u0.y, u0.z, u0.w, u1.x, u1.y, u1.z, u1.w, u8};
                    #pragma unroll
                    for (int c = 0; c < 9; ++c) {
                        acc[0][c] = fmaf(uu[c], q0, acc[0][c]);
                        acc[1][c] = fmaf(uu[c], q1, acc[1][c]);
                        acc[2][c] = fmaf(uu[c], q2, acc[2][c]);
                        acc[3][c] = fmaf(uu[c], q3, acc[3][c]);
                    }
                    ++ab;
                }
            }
            #pragma unroll
            for (int n = 0; n < NB; ++n)
                #pragma unroll
                for (int c = 0; c < 9; ++c) s_hc[n][c][p] = acc[n][c];
        }
        __syncthreads();   // tp visible to all columns (linear_out reads all p)

        // ---------- step 4: linear_out, p-split + l-fused, P-step 8, dbuf weights
        // each nh-half sums its 128 p's for ALL 4 nodes, then halves are exchanged
        {
            const float* V0 = W_out + (size_t)(it * 3 + 0) * PCH * KCH + kk;
            const float* V1 = W_out + (size_t)(it * 3 + 1) * PCH * KCH + kk;
            const float* V2 = W_out + (size_t)(it * 3 + 2) * PCH * KCH + kk;
            const int pb0 = nh * 128;   // this half's p-range

            float acc[NB][9];
            #pragma unroll
            for (int n = 0; n < NB; ++n)
                #pragma unroll
                for (int m = 0; m < 9; ++m) acc[n][m] = 0.0f;

            float wa[3][8], wb[3][8];
            LOADWOUT(wa, 0);
            #pragma unroll 1
            for (int pb = 0; pb < 128 - 16; pb += 16) {
                LOADWOUT(wb, pb + 8);
                OUTSTEP(wa, pb);
                LOADWOUT(wa, pb + 16);
                OUTSTEP(wb, pb + 8);
            }
            {   // tail: pb = 112
                LOADWOUT(wb, 120);
                OUTSTEP(wa, 112);
                OUTSTEP(wb, 120);
            }

            // exchange: give the other half the partials for ITS nodes.
            // s_red aliases s_h (dead: last read was linear_in, ordered by the
            // post-TP barrier above). writes are lane-consecutive -> conflict-free.
            if (nh == 0) {
                #pragma unroll
                for (int j = 0; j < 18; ++j)
                    s_red[0][j][kk] = acc[2 + j / 9][j % 9];   // nodes 2,3
            } else {
                #pragma unroll
                for (int j = 0; j < 18; ++j)
                    s_red[1][j][kk] = acc[j / 9][j % 9];       // nodes 0,1
            }
            __syncthreads();

            const int ob = 1 - nh;   // buffer written by the other half
            #pragma unroll
            for (int j = 0; j < 2; ++j)
                #pragma unroll
                for (int m = 0; m < 9; ++m)
                    f[j][m] += acc[2 * nh + j][m] + s_red[ob][j * 9 + m][kk];
        }
        __syncthreads();   // s_red reads done before next iter's RMS rewrites s_h
    }

    // ---------- store packed output (N, 9, K)
    #pragma unroll
    for (int j = 0; j < 2; ++j) {
        const int n = node0 + 2 * nh + j;
        #pragma unroll
        for (int m = 0; m < 9; ++m)
            out[(size_t)(n * 9 + m) * KCH + kk] = f[j][m];
    }
}

extern "C" void kernel_launch(void* const* d_in, const int* in_sizes, int n_in,
                              void* d_out, int out_size, void* d_ws, size_t ws_size,
                              hipStream_t stream) {
    const float* f0    = (const float*)d_in[0];
    const float* f1    = (const float*)d_in[1];
    const float* f2    = (const float*)d_in[2];
    const float* U     = (const float*)d_in[3];
    const float* gamma = (const float*)d_in[4];
    const float* W_in  = (const float*)d_in[5];
    const float* W_out = (const float*)d_in[6];
    float* out = (float*)d_out;

    dim3 grid(NNODES / NB);   // 50000 / 4 = 12500, exact
    dim3 block(256);
    hipLaunchKernelGGL(cg_fused, grid, block, 0, stream,
                       f0, f1, f2, U, gamma, W_in, W_out, out);
}

// Round 2
// 7764.088 us; speedup vs baseline: 1.3405x; 1.3405x over previous
//
#include <hip/hip_runtime.h>

// CGIterator: N=50000 nodes, K=128, I=4 chained CG iterations, fp32.
// Fully fused: one block = 4 nodes through all 4 iterations.
// Thread owns (node-pair, k) for norm/skip; owns column p for channel mixing.
//
// Register-pressure-safe revision of the l-fused/double-buffered scheme:
//  - l-fused K-steps of 4 (not 8): 144 FMAs per 12-load batch, wa+wb = 24 regs
//  - f[] skip-state lives in LDS (s_f, thread-private elements) -> -18 VGPRs
//  - linear_out p-split: each half sums 128 p's for ALL 4 nodes (W_out read
//    once per block), 18-float conflict-free LDS exchange aliased on dead s_h

#define NNODES 50000
#define KCH 128          // K
#define PCH 256          // 2K
#define NITER 4
#define NB 4             // nodes per block

// ---- linear_in helpers: acc[NB][9] over s_h, weights buf[3][4] ----
#define LOADWIN(buf, kb) do { \
    _Pragma("unroll") \
    for (int r = 0; r < 4; ++r) { \
        buf[0][r] = W0[((kb) + r) * PCH]; \
        buf[1][r] = W1[((kb) + r) * PCH]; \
        buf[2][r] = W2[((kb) + r) * PCH]; \
    } \
} while (0)

#define INSTEP(buf, kb) do { \
    _Pragma("unroll") \
    for (int n = 0; n < NB; ++n) { \
        _Pragma("unroll") \
        for (int m = 0; m < 9; ++m) { \
            const int lm = (m == 0) ? 0 : ((m < 4) ? 1 : 2); \
            const float4 h4 = *(const float4*)&s_h[n][m][(kb)]; \
            float a = acc[n][m]; \
            a = fmaf(h4.x, buf[lm][0], a); \
            a = fmaf(h4.y, buf[lm][1], a); \
            a = fmaf(h4.z, buf[lm][2], a); \
            a = fmaf(h4.w, buf[lm][3], a); \
            acc[n][m] = a; \
        } \
    } \
} while (0)

// ---- linear_out helpers: acc[NB][9] over s_hc (own p-half), weights buf[3][4]
#define LOADWOUT(buf, pb) do { \
    _Pragma("unroll") \
    for (int r = 0; r < 4; ++r) { \
        buf[0][r] = V0[(size_t)(pb0 + (pb) + r) * KCH]; \
        buf[1][r] = V1[(size_t)(pb0 + (pb) + r) * KCH]; \
        buf[2][r] = V2[(size_t)(pb0 + (pb) + r) * KCH]; \
    } \
} while (0)

#define OUTSTEP(buf, pb) do { \
    _Pragma("unroll") \
    for (int n = 0; n < NB; ++n) { \
        _Pragma("unroll") \
        for (int m = 0; m < 9; ++m) { \
            const int lm = (m == 0) ? 0 : ((m < 4) ? 1 : 2); \
            const float4 t4 = *(const float4*)&s_hc[n][m][pb0 + (pb)]; \
            float a = acc[n][m]; \
            a = fmaf(t4.x, buf[lm][0], a); \
            a = fmaf(t4.y, buf[lm][1], a); \
            a = fmaf(t4.z, buf[lm][2], a); \
            a = fmaf(t4.w, buf[lm][3], a); \
            acc[n][m] = a; \
        } \
    } \
} while (0)

__global__ __launch_bounds__(256, 2)
void cg_fused(const float* __restrict__ f0,
              const float* __restrict__ f1,
              const float* __restrict__ f2,
              const float* __restrict__ Uin,
              const float* __restrict__ gamma,
              const float* __restrict__ W_in,
              const float* __restrict__ W_out,
              float* __restrict__ out)
{
    // symmetrized U, upper triangle a<=b packed: sUp[ab][c], c padded to 12 for b128
    __shared__ float sUp[45][12];
    __shared__ float s_h[NB][9][KCH];    // RMS-normed feats; dead after linear_in,
                                         // reused as the linear_out exchange buffer
    __shared__ float s_hc[NB][9][PCH];   // hc, overwritten in place by tp
    __shared__ float s_f[NB][9][KCH];    // skip-state f (thread-private elements)

    // exchange view: s_red[half][j=node2*9+m][kk], 2*18*128*4B == sizeof(s_h)
    float (*s_red)[18][KCH] = reinterpret_cast<float (*)[18][KCH]>(&s_h[0][0][0]);

    const int tid = threadIdx.x;
    const int node0 = blockIdx.x * NB;

    // ---- build symmetrized padded U in LDS (once per block)
    for (int idx = tid; idx < 45 * 12; idx += 256) {
        const int ab = idx / 12;
        const int c  = idx % 12;
        int a = 0, r = ab;
        while (r >= 9 - a) { r -= 9 - a; ++a; }
        const int b = a + r;
        float v = 0.0f;
        if (c < 9) {
            v = Uin[(a * 9 + b) * 9 + c];
            if (a != b) v += Uin[(b * 9 + a) * 9 + c];
        }
        sUp[ab][c] = v;
    }

    const int kk = tid & (KCH - 1);  // channel 0..127
    const int nh = tid >> 7;         // node-half: 0 or 1 (wave-uniform)
    const int p  = tid;              // expanded channel column 0..255

    // ---- load initial feats into s_f: thread owns nodes 2*nh+{0,1}, channel kk
    #pragma unroll
    for (int j = 0; j < 2; ++j) {
        const int n  = node0 + 2 * nh + j;
        const int nl = 2 * nh + j;
        s_f[nl][0][kk] = f0[n * KCH + kk];
        #pragma unroll
        for (int m = 0; m < 3; ++m) s_f[nl][1 + m][kk] = f1[(n * 3 + m) * KCH + kk];
        #pragma unroll
        for (int m = 0; m < 5; ++m) s_f[nl][4 + m][kk] = f2[(n * 5 + m) * KCH + kk];
    }

    for (int it = 0; it < NITER; ++it) {
        // ---------- step 1: equivariant RMS norm  s_f -> s_h ----------
        const float g0 = gamma[(it * 3 + 0) * KCH + kk];
        const float g1 = gamma[(it * 3 + 1) * KCH + kk];
        const float g2 = gamma[(it * 3 + 2) * KCH + kk];
        #pragma unroll
        for (int j = 0; j < 2; ++j) {
            const int nl = 2 * nh + j;
            float fj[9];
            #pragma unroll
            for (int m = 0; m < 9; ++m) fj[m] = s_f[nl][m][kk];
            const float s0 = fj[0] * fj[0];
            const float s1 = fj[1] * fj[1] + fj[2] * fj[2] + fj[3] * fj[3];
            const float s2 = fj[4] * fj[4] + fj[5] * fj[5] + fj[6] * fj[6]
                           + fj[7] * fj[7] + fj[8] * fj[8];
            const float r0 = rsqrtf(s0 + 1e-6f) * g0;
            const float r1 = rsqrtf(s1 * (1.0f / 3.0f) + 1e-6f) * g1;
            const float r2 = rsqrtf(s2 * (1.0f / 5.0f) + 1e-6f) * g2;
            s_h[nl][0][kk] = fj[0] * r0;
            s_h[nl][1][kk] = fj[1] * r1;
            s_h[nl][2][kk] = fj[2] * r1;
            s_h[nl][3][kk] = fj[3] * r1;
            s_h[nl][4][kk] = fj[4] * r2;
            s_h[nl][5][kk] = fj[5] * r2;
            s_h[nl][6][kk] = fj[6] * r2;
            s_h[nl][7][kk] = fj[7] * r2;
            s_h[nl][8][kk] = fj[8] * r2;
        }
        __syncthreads();   // s_h visible to all (also orders sUp build on it==0)

        // ---------- step 2: linear_in, l-fused, K-step 4, double-buffered weights
        {
            const float* W0 = W_in + (size_t)(it * 3 + 0) * KCH * PCH + p;
            const float* W1 = W_in + (size_t)(it * 3 + 1) * KCH * PCH + p;
            const float* W2 = W_in + (size_t)(it * 3 + 2) * KCH * PCH + p;
            float acc[NB][9];
            #pragma unroll
            for (int n = 0; n < NB; ++n)
                #pragma unroll
                for (int m = 0; m < 9; ++m) acc[n][m] = 0.0f;

            float wa[3][4], wb[3][4];
            LOADWIN(wa, 0);
            #pragma unroll 1
            for (int kb = 0; kb < KCH - 8; kb += 8) {
                LOADWIN(wb, kb + 4);
                INSTEP(wa, kb);
                LOADWIN(wa, kb + 8);
                INSTEP(wb, kb + 4);
            }
            {   // tail: kb = 120, 124
                LOADWIN(wb, 124);
                INSTEP(wa, 120);
                INSTEP(wb, 124);
            }
            #pragma unroll
            for (int n = 0; n < NB; ++n)
                #pragma unroll
                for (int m = 0; m < 9; ++m)
                    s_hc[n][m][p] = acc[n][m];
        }
        // no barrier: s_hc column p is written and read by the same thread

        // ---------- step 3: channel-wise CG tensor product (in place, own column p)
        {
            float v[NB][9];
            #pragma unroll
            for (int n = 0; n < NB; ++n)
                #pragma unroll
                for (int a = 0; a < 9; ++a) v[n][a] = s_hc[n][a][p];

            float acc[NB][9];
            #pragma unroll
            for (int n = 0; n < NB; ++n)
                #pragma unroll
                for (int c = 0; c < 9; ++c) acc[n][c] = 0.0f;

            int ab = 0;
            #pragma unroll
            for (int a = 0; a < 9; ++a) {
                #pragma unroll
                for (int b = a; b < 9; ++b) {
                    const float q0 = v[0][a] * v[0][b];
                    const float q1 = v[1][a] * v[1][b];
                    const float q2 = v[2][a] * v[2][b];
                    const float q3 = v[3][a] * v[3][b];
                    const float4 u0 = *(const float4*)&sUp[ab][0];
                    const float4 u1 = *(const float4*)&sUp[ab][4];
                    const float  u8 = sUp[ab][8];
                    const float uu[9] = {u0.x, u0.y, u0.z, u0.w, u1.x, u1.y, u1.z, u1.w, u8};
                    #pragma unroll
                    for (int c = 0; c < 9; ++c) {
                        acc[0][c] = fmaf(uu[c], q0, acc[0][c]);
                        acc[1][c] = fmaf(uu[c], q1, acc[1][c]);
                        acc[2][c] = fmaf(uu[c], q2, acc[2][c]);
                        acc[3][c] = fmaf(uu[c], q3, acc[3][c]);
                    }
                    ++ab;
                }
            }
            #pragma unroll
            for (int n = 0; n < NB; ++n)
                #pragma unroll
                for (int c = 0; c < 9; ++c) s_hc[n][c][p] = acc[n][c];
        }
        __syncthreads();   // tp visible to all columns (linear_out reads all p)

        // ---------- step 4: linear_out, p-split + l-fused, P-step 4, dbuf weights
        // each nh-half sums its 128 p's for ALL 4 nodes, then halves are exchanged
        {
            const float* V0 = W_out + (size_t)(it * 3 + 0) * PCH * KCH + kk;
            const float* V1 = W_out + (size_t)(it * 3 + 1) * PCH * KCH + kk;
            const float* V2 = W_out + (size_t)(it * 3 + 2) * PCH * KCH + kk;
            const int pb0 = nh * 128;   // this half's p-range (wave-uniform)

            float acc[NB][9];
            #pragma unroll
            for (int n = 0; n < NB; ++n)
                #pragma unroll
                for (int m = 0; m < 9; ++m) acc[n][m] = 0.0f;

            float wa[3][4], wb[3][4];
            LOADWOUT(wa, 0);
            #pragma unroll 1
            for (int pb = 0; pb < 128 - 8; pb += 8) {
                LOADWOUT(wb, pb + 4);
                OUTSTEP(wa, pb);
                LOADWOUT(wa, pb + 8);
                OUTSTEP(wb, pb + 4);
            }
            {   // tail: pb = 120, 124
                LOADWOUT(wb, 124);
                OUTSTEP(wa, 120);
                OUTSTEP(wb, 124);
            }

            // exchange: give the other half the partials for ITS nodes.
            // s_red aliases s_h (dead: last read was linear_in, ordered by the
            // post-TP barrier above). writes are lane-consecutive -> conflict-free.
            if (nh == 0) {
                #pragma unroll
                for (int j = 0; j < 18; ++j)
                    s_red[0][j][kk] = acc[2 + j / 9][j % 9];   // nodes 2,3
            } else {
                #pragma unroll
                for (int j = 0; j < 18; ++j)
                    s_red[1][j][kk] = acc[j / 9][j % 9];       // nodes 0,1
            }
            __syncthreads();

            const int ob = 1 - nh;   // buffer written by the other half
            #pragma unroll
            for (int j = 0; j < 2; ++j) {
                const int nl = 2 * nh + j;
                #pragma unroll
                for (int m = 0; m < 9; ++m)
                    s_f[nl][m][kk] += acc[nl][m] + s_red[ob][j * 9 + m][kk];
            }
        }
        __syncthreads();   // s_red reads done before next iter's RMS rewrites s_h
    }

    // ---------- store packed output (N, 9, K)
    #pragma unroll
    for (int j = 0; j < 2; ++j) {
        const int n  = node0 + 2 * nh + j;
        const int nl = 2 * nh + j;
        #pragma unroll
        for (int m = 0; m < 9; ++m)
            out[(size_t)(n * 9 + m) * KCH + kk] = s_f[nl][m][kk];
    }
}

extern "C" void kernel_launch(void* const* d_in, const int* in_sizes, int n_in,
                              void* d_out, int out_size, void* d_ws, size_t ws_size,
                              hipStream_t stream) {
    const float* f0    = (const float*)d_in[0];
    const float* f1    = (const float*)d_in[1];
    const float* f2    = (const float*)d_in[2];
    const float* U     = (const float*)d_in[3];
    const float* gamma = (const float*)d_in[4];
    const float* W_in  = (const float*)d_in[5];
    const float* W_out = (const float*)d_in[6];
    float* out = (float*)d_out;

    dim3 grid(NNODES / NB);   // 50000 / 4 = 12500, exact
    dim3 block(256);
    hipLaunchKernelGGL(cg_fused, grid, block, 0, stream,
                       f0, f1, f2, U, gamma, W_in, W_out, out);
}

// Round 3
// 6111.817 us; speedup vs baseline: 1.7029x; 1.2703x over previous
//
#include <hip/hip_runtime.h>

// CGIterator: N=50000 nodes, K=128, I=4 chained CG iterations, fp32.
// NB=2 nodes/block, 256 threads, 25000 blocks.
//  - latency-bound fix: 4 blocks/CU (LDS ~30 KB, VGPR<=128) = 16 waves/CU,
//    2x the latency hiding of the NB=4 variant
//  - l-fused dbuf weight prefetch (K-step 4): 72 FMAs cover each 12-load batch
//  - TP consumes lin_in accumulators directly in registers (no hc round-trip)
//  - p-split linear_out: W_out read once per block; 9-float LDS exchange
//    (aliased on dead s_h); all register indices compile-time (no scratch)

#define NNODES 50000
#define KCH 128          // K
#define PCH 256          // 2K
#define NITER 4
#define NB 2             // nodes per block

// ---- linear_in: weights buf[3][4] at column p, acc hc[2][9] over s_h ----
#define LOADWIN(buf, kb) do { \
    _Pragma("unroll") \
    for (int r = 0; r < 4; ++r) { \
        buf[0][r] = W0[((kb) + r) * PCH]; \
        buf[1][r] = W1[((kb) + r) * PCH]; \
        buf[2][r] = W2[((kb) + r) * PCH]; \
    } \
} while (0)

#define INSTEP(buf, kb) do { \
    _Pragma("unroll") \
    for (int n = 0; n < NB; ++n) { \
        _Pragma("unroll") \
        for (int m = 0; m < 9; ++m) { \
            const int lm = (m == 0) ? 0 : ((m < 4) ? 1 : 2); \
            const float4 h4 = *(const float4*)&s_h[n][m][(kb)]; \
            float a = hc[n][m]; \
            a = fmaf(h4.x, buf[lm][0], a); \
            a = fmaf(h4.y, buf[lm][1], a); \
            a = fmaf(h4.z, buf[lm][2], a); \
            a = fmaf(h4.w, buf[lm][3], a); \
            hc[n][m] = a; \
        } \
    } \
} while (0)

// ---- linear_out: weights buf[3][4] at row-range pb0+pb, acc oacc[2][9] over s_tp
#define LOADWOUT(buf, pb) do { \
    _Pragma("unroll") \
    for (int r = 0; r < 4; ++r) { \
        buf[0][r] = V0[(size_t)(pb0 + (pb) + r) * KCH]; \
        buf[1][r] = V1[(size_t)(pb0 + (pb) + r) * KCH]; \
        buf[2][r] = V2[(size_t)(pb0 + (pb) + r) * KCH]; \
    } \
} while (0)

#define OUTSTEP(buf, pb) do { \
    _Pragma("unroll") \
    for (int n = 0; n < NB; ++n) { \
        _Pragma("unroll") \
        for (int m = 0; m < 9; ++m) { \
            const int lm = (m == 0) ? 0 : ((m < 4) ? 1 : 2); \
            const float4 t4 = *(const float4*)&s_tp[n][m][pb0 + (pb)]; \
            float a = oacc[n][m]; \
            a = fmaf(t4.x, buf[lm][0], a); \
            a = fmaf(t4.y, buf[lm][1], a); \
            a = fmaf(t4.z, buf[lm][2], a); \
            a = fmaf(t4.w, buf[lm][3], a); \
            oacc[n][m] = a; \
        } \
    } \
} while (0)

__global__ __launch_bounds__(256, 4)
void cg_fused(const float* __restrict__ f0,
              const float* __restrict__ f1,
              const float* __restrict__ f2,
              const float* __restrict__ Uin,
              const float* __restrict__ gamma,
              const float* __restrict__ W_in,
              const float* __restrict__ W_out,
              float* __restrict__ out)
{
    // symmetrized U, upper triangle a<=b packed: sUp[ab][c], c padded to 12
    __shared__ float sUp[45][12];                 // 2.1 KB
    __shared__ float s_h[NB][9][KCH];             // 9.2 KB; dead after linear_in,
                                                  // reused as linear_out exchange
    __shared__ float s_tp[NB][9][PCH];            // 18.4 KB, TP output

    // exchange view: s_red[half][m][kk], 2*9*128*4B == sizeof(s_h)
    float (*s_red)[9][KCH] = reinterpret_cast<float (*)[9][KCH]>(&s_h[0][0][0]);

    const int tid = threadIdx.x;
    const int node0 = blockIdx.x * NB;

    // ---- build symmetrized padded U in LDS (once per block)
    for (int idx = tid; idx < 45 * 12; idx += 256) {
        const int ab = idx / 12;
        const int c  = idx % 12;
        int a = 0, r = ab;
        while (r >= 9 - a) { r -= 9 - a; ++a; }
        const int b = a + r;
        float v = 0.0f;
        if (c < 9) {
            v = Uin[(a * 9 + b) * 9 + c];
            if (a != b) v += Uin[(b * 9 + a) * 9 + c];
        }
        sUp[ab][c] = v;
    }

    const int kk = tid & (KCH - 1);   // channel 0..127
    const int nh = tid >> 7;          // node / p-half: 0 or 1 (wave-uniform)
    const int p  = tid;               // expanded channel column 0..255
    const int n_glob = node0 + nh;

    // ---- initial feats: thread owns (node nh, channel kk), all 9 m — registers
    float f[9];
    f[0] = f0[n_glob * KCH + kk];
    #pragma unroll
    for (int m = 0; m < 3; ++m) f[1 + m] = f1[(n_glob * 3 + m) * KCH + kk];
    #pragma unroll
    for (int m = 0; m < 5; ++m) f[4 + m] = f2[(n_glob * 5 + m) * KCH + kk];

    for (int it = 0; it < NITER; ++it) {
        // ---------- step 1: equivariant RMS norm -> s_h ----------
        {
            const float g0 = gamma[(it * 3 + 0) * KCH + kk];
            const float g1 = gamma[(it * 3 + 1) * KCH + kk];
            const float g2 = gamma[(it * 3 + 2) * KCH + kk];
            const float s0 = f[0] * f[0];
            const float s1 = f[1] * f[1] + f[2] * f[2] + f[3] * f[3];
            const float s2 = f[4] * f[4] + f[5] * f[5] + f[6] * f[6]
                           + f[7] * f[7] + f[8] * f[8];
            const float r0 = rsqrtf(s0 + 1e-6f) * g0;
            const float r1 = rsqrtf(s1 * (1.0f / 3.0f) + 1e-6f) * g1;
            const float r2 = rsqrtf(s2 * (1.0f / 5.0f) + 1e-6f) * g2;
            s_h[nh][0][kk] = f[0] * r0;
            s_h[nh][1][kk] = f[1] * r1;
            s_h[nh][2][kk] = f[2] * r1;
            s_h[nh][3][kk] = f[3] * r1;
            s_h[nh][4][kk] = f[4] * r2;
            s_h[nh][5][kk] = f[5] * r2;
            s_h[nh][6][kk] = f[6] * r2;
            s_h[nh][7][kk] = f[7] * r2;
            s_h[nh][8][kk] = f[8] * r2;
        }
        __syncthreads();   // s_h visible (also orders sUp build on it==0)

        // ---------- step 2: linear_in, l-fused, K-step 4, dbuf weights ----------
        float hc[NB][9];   // this thread's hc column p — stays in registers for TP
        {
            const float* W0 = W_in + (size_t)(it * 3 + 0) * KCH * PCH + p;
            const float* W1 = W_in + (size_t)(it * 3 + 1) * KCH * PCH + p;
            const float* W2 = W_in + (size_t)(it * 3 + 2) * KCH * PCH + p;
            #pragma unroll
            for (int n = 0; n < NB; ++n)
                #pragma unroll
                for (int m = 0; m < 9; ++m) hc[n][m] = 0.0f;

            float wa[3][4], wb[3][4];
            LOADWIN(wa, 0);
            #pragma unroll 1
            for (int kb = 0; kb < KCH - 8; kb += 8) {
                LOADWIN(wb, kb + 4);
                INSTEP(wa, kb);
                LOADWIN(wa, kb + 8);
                INSTEP(wb, kb + 4);
            }
            {   // tail: kb = 120, 124
                LOADWIN(wb, 124);
                INSTEP(wa, 120);
                INSTEP(wb, 124);
            }
        }

        // prefetch linear_out's first weight batch under the TP compute
        const float* V0 = W_out + (size_t)(it * 3 + 0) * PCH * KCH + kk;
        const float* V1 = W_out + (size_t)(it * 3 + 1) * PCH * KCH + kk;
        const float* V2 = W_out + (size_t)(it * 3 + 2) * PCH * KCH + kk;
        const int pb0 = nh * 128;   // this half's p-range (wave-uniform)
        float va[3][4];
        LOADWOUT(va, 0);

        // ---------- step 3: CG tensor product, all in registers ----------
        {
            float tp[NB][9];
            #pragma unroll
            for (int n = 0; n < NB; ++n)
                #pragma unroll
                for (int c = 0; c < 9; ++c) tp[n][c] = 0.0f;

            int ab = 0;
            #pragma unroll
            for (int a = 0; a < 9; ++a) {
                #pragma unroll
                for (int b = a; b < 9; ++b) {
                    const float q0 = hc[0][a] * hc[0][b];
                    const float q1 = hc[1][a] * hc[1][b];
                    const float4 u0 = *(const float4*)&sUp[ab][0];
                    const float4 u1 = *(const float4*)&sUp[ab][4];
                    const float  u8 = sUp[ab][8];
                    const float uu[9] = {u0.x, u0.y, u0.z, u0.w, u1.x, u1.y, u1.z, u1.w, u8};
                    #pragma unroll
                    for (int c = 0; c < 9; ++c) {
                        tp[0][c] = fmaf(uu[c], q0, tp[0][c]);
                        tp[1][c] = fmaf(uu[c], q1, tp[1][c]);
                    }
                    ++ab;
                }
            }
            #pragma unroll
            for (int n = 0; n < NB; ++n)
                #pragma unroll
                for (int c = 0; c < 9; ++c) s_tp[n][c][p] = tp[n][c];
        }
        __syncthreads();   // tp visible to all columns (linear_out reads all p)

        // ---------- step 4: linear_out, p-split + l-fused, dbuf ----------
        {
            float oacc[NB][9];
            #pragma unroll
            for (int n = 0; n < NB; ++n)
                #pragma unroll
                for (int m = 0; m < 9; ++m) oacc[n][m] = 0.0f;

            float vb[3][4];
            #pragma unroll 1
            for (int pb = 0; pb < 128 - 8; pb += 8) {
                LOADWOUT(vb, pb + 4);
                OUTSTEP(va, pb);
                LOADWOUT(va, pb + 8);
                OUTSTEP(vb, pb + 4);
            }
            {   // tail: pb = 120, 124
                LOADWOUT(vb, 124);
                OUTSTEP(va, 120);
                OUTSTEP(vb, 124);
            }

            // exchange: each thread hands the other half its partial for the
            // OTHER node (9 floats). wave-uniform selects, compile-time indices.
            float own[9], wr[9];
            #pragma unroll
            for (int m = 0; m < 9; ++m) {
                own[m] = (nh == 0) ? oacc[0][m] : oacc[1][m];
                wr[m]  = (nh == 0) ? oacc[1][m] : oacc[0][m];
            }
            #pragma unroll
            for (int m = 0; m < 9; ++m)
                s_red[nh][m][kk] = wr[m];    // s_red aliases dead s_h
            __syncthreads();

            const int other = nh ^ 1;
            #pragma unroll
            for (int m = 0; m < 9; ++m)
                f[m] += own[m] + s_red[other][m][kk];
        }
        __syncthreads();   // s_red reads done before next iter's RMS rewrites s_h
    }

    // ---------- store packed output (N, 9, K)
    #pragma unroll
    for (int m = 0; m < 9; ++m)
        out[(size_t)(n_glob * 9 + m) * KCH + kk] = f[m];
}

extern "C" void kernel_launch(void* const* d_in, const int* in_sizes, int n_in,
                              void* d_out, int out_size, void* d_ws, size_t ws_size,
                              hipStream_t stream) {
    const float* f0    = (const float*)d_in[0];
    const float* f1    = (const float*)d_in[1];
    const float* f2    = (const float*)d_in[2];
    const float* U     = (const float*)d_in[3];
    const float* gamma = (const float*)d_in[4];
    const float* W_in  = (const float*)d_in[5];
    const float* W_out = (const float*)d_in[6];
    float* out = (float*)d_out;

    dim3 grid(NNODES / NB);   // 50000 / 2 = 25000, exact
    dim3 block(256);
    hipLaunchKernelGGL(cg_fused, grid, block, 0, stream,
                       f0, f1, f2, U, gamma, W_in, W_out, out);
}

// Round 5
// 5942.722 us; speedup vs baseline: 1.7514x; 1.0285x over previous
//
#include <hip/hip_runtime.h>

// CGIterator: N=50000 nodes, K=128, I=4 chained CG iterations, fp32.
// Round-4 theory: kernel is LDS-instruction-throughput-bound (~8 cyc per
// wave64 ds_read_b128, broadcast or not). Fix = halve ds_read count per FMA:
//  - 128 threads/block (2 waves), NB=2 nodes
//  - linear_in: thread owns TWO columns (p, p+128) -> each s_h b128 feeds 8 FMAs
//  - linear_out: thread owns TWO kk (ln, ln+64), wave owns a p-half -> same 2x
//  - TP: both columns share each sUp read
//  - single-buffered weights (24 regs), unroll 1, peak live ~110 VGPR (no spill)

#define NNODES 50000
#define KCH 128          // K
#define PCH 256          // 2K
#define NITER 4
#define NB 2             // nodes per block
#define NTHR 128

__global__ __launch_bounds__(NTHR, 4)
void cg_fused(const float* __restrict__ f0,
              const float* __restrict__ f1,
              const float* __restrict__ f2,
              const float* __restrict__ Uin,
              const float* __restrict__ gamma,
              const float* __restrict__ W_in,
              const float* __restrict__ W_out,
              float* __restrict__ out)
{
    // symmetrized U, upper triangle a<=b packed: sUp[ab][c], c padded to 12
    __shared__ float sUp[45][12];                 // 2.1 KB
    __shared__ float s_h[NB][9][KCH];             // 9.2 KB; dead after linear_in,
                                                  // aliased as exchange buffer
    __shared__ float s_tp[NB][9][PCH];            // 18.4 KB, TP output

    // exchange view: s_red[j = n*9+m][kk], 18*128*4B == sizeof(s_h)
    float (*s_red)[KCH] = reinterpret_cast<float (*)[KCH]>(&s_h[0][0][0]);

    const int tid = threadIdx.x;      // 0..127
    const int w   = tid >> 6;         // wave: 0 or 1 (uniform per wave)
    const int ln  = tid & 63;
    const int kk  = tid;              // owned channel for RMS/skip/output
    const int node0 = blockIdx.x * NB;

    // ---- build symmetrized padded U in LDS (once per block)
    for (int idx = tid; idx < 45 * 12; idx += NTHR) {
        const int ab = idx / 12;
        const int c  = idx % 12;
        int a = 0, r = ab;
        while (r >= 9 - a) { r -= 9 - a; ++a; }
        const int b = a + r;
        float v = 0.0f;
        if (c < 9) {
            v = Uin[(a * 9 + b) * 9 + c];
            if (a != b) v += Uin[(b * 9 + a) * 9 + c];
        }
        sUp[ab][c] = v;
    }

    // ---- initial feats: thread owns channel kk for BOTH nodes, all 9 m
    float f[NB][9];
    #pragma unroll
    for (int n = 0; n < NB; ++n) {
        const int ng = node0 + n;
        f[n][0] = f0[ng * KCH + kk];
        #pragma unroll
        for (int m = 0; m < 3; ++m) f[n][1 + m] = f1[(ng * 3 + m) * KCH + kk];
        #pragma unroll
        for (int m = 0; m < 5; ++m) f[n][4 + m] = f2[(ng * 5 + m) * KCH + kk];
    }

    for (int it = 0; it < NITER; ++it) {
        // ---------- step 1: equivariant RMS norm -> s_h ----------
        {
            const float g0 = gamma[(it * 3 + 0) * KCH + kk];
            const float g1 = gamma[(it * 3 + 1) * KCH + kk];
            const float g2 = gamma[(it * 3 + 2) * KCH + kk];
            #pragma unroll
            for (int n = 0; n < NB; ++n) {
                const float s0 = f[n][0] * f[n][0];
                const float s1 = f[n][1] * f[n][1] + f[n][2] * f[n][2] + f[n][3] * f[n][3];
                const float s2 = f[n][4] * f[n][4] + f[n][5] * f[n][5] + f[n][6] * f[n][6]
                               + f[n][7] * f[n][7] + f[n][8] * f[n][8];
                const float r0 = rsqrtf(s0 + 1e-6f) * g0;
                const float r1 = rsqrtf(s1 * (1.0f / 3.0f) + 1e-6f) * g1;
                const float r2 = rsqrtf(s2 * (1.0f / 5.0f) + 1e-6f) * g2;
                s_h[n][0][kk] = f[n][0] * r0;
                s_h[n][1][kk] = f[n][1] * r1;
                s_h[n][2][kk] = f[n][2] * r1;
                s_h[n][3][kk] = f[n][3] * r1;
                s_h[n][4][kk] = f[n][4] * r2;
                s_h[n][5][kk] = f[n][5] * r2;
                s_h[n][6][kk] = f[n][6] * r2;
                s_h[n][7][kk] = f[n][7] * r2;
                s_h[n][8][kk] = f[n][8] * r2;
            }
        }
        __syncthreads();   // s_h visible (also orders sUp build on it==0)

        // ---------- step 2: linear_in, 2 columns/thread (p=tid, p+128) ----------
        float hcA[NB][9], hcB[NB][9];
        {
            const float* W0 = W_in + (size_t)(it * 3 + 0) * KCH * PCH + tid;
            const float* W1 = W_in + (size_t)(it * 3 + 1) * KCH * PCH + tid;
            const float* W2 = W_in + (size_t)(it * 3 + 2) * KCH * PCH + tid;
            #pragma unroll
            for (int n = 0; n < NB; ++n)
                #pragma unroll
                for (int m = 0; m < 9; ++m) { hcA[n][m] = 0.0f; hcB[n][m] = 0.0f; }

            #pragma unroll 1
            for (int kb = 0; kb < KCH; kb += 4) {
                float wv[3][4][2];
                #pragma unroll
                for (int r = 0; r < 4; ++r) {
                    wv[0][r][0] = W0[(kb + r) * PCH];
                    wv[0][r][1] = W0[(kb + r) * PCH + 128];
                    wv[1][r][0] = W1[(kb + r) * PCH];
                    wv[1][r][1] = W1[(kb + r) * PCH + 128];
                    wv[2][r][0] = W2[(kb + r) * PCH];
                    wv[2][r][1] = W2[(kb + r) * PCH + 128];
                }
                #pragma unroll
                for (int n = 0; n < NB; ++n) {
                    #pragma unroll
                    for (int m = 0; m < 9; ++m) {
                        const int lm = (m == 0) ? 0 : ((m < 4) ? 1 : 2);
                        const float4 h4 = *(const float4*)&s_h[n][m][kb];
                        float a = hcA[n][m], b = hcB[n][m];
                        a = fmaf(h4.x, wv[lm][0][0], a);
                        a = fmaf(h4.y, wv[lm][1][0], a);
                        a = fmaf(h4.z, wv[lm][2][0], a);
                        a = fmaf(h4.w, wv[lm][3][0], a);
                        b = fmaf(h4.x, wv[lm][0][1], b);
                        b = fmaf(h4.y, wv[lm][1][1], b);
                        b = fmaf(h4.z, wv[lm][2][1], b);
                        b = fmaf(h4.w, wv[lm][3][1], b);
                        hcA[n][m] = a; hcB[n][m] = b;
                    }
                }
            }
        }

        // ---------- step 3: CG tensor product, both columns in registers ----------
        {
            float tpA[NB][9], tpB[NB][9];
            #pragma unroll
            for (int n = 0; n < NB; ++n)
                #pragma unroll
                for (int c = 0; c < 9; ++c) { tpA[n][c] = 0.0f; tpB[n][c] = 0.0f; }

            int ab = 0;
            #pragma unroll
            for (int a = 0; a < 9; ++a) {
                #pragma unroll
                for (int b = a; b < 9; ++b) {
                    const float qA0 = hcA[0][a] * hcA[0][b];
                    const float qA1 = hcA[1][a] * hcA[1][b];
                    const float qB0 = hcB[0][a] * hcB[0][b];
                    const float qB1 = hcB[1][a] * hcB[1][b];
                    const float4 u0 = *(const float4*)&sUp[ab][0];
                    const float4 u1 = *(const float4*)&sUp[ab][4];
                    const float  u8 = sUp[ab][8];
                    const float uu[9] = {u0.x, u0.y, u0.z, u0.w, u1.x, u1.y, u1.z, u1.w, u8};
                    #pragma unroll
                    for (int c = 0; c < 9; ++c) {
                        tpA[0][c] = fmaf(uu[c], qA0, tpA[0][c]);
                        tpA[1][c] = fmaf(uu[c], qA1, tpA[1][c]);
                        tpB[0][c] = fmaf(uu[c], qB0, tpB[0][c]);
                        tpB[1][c] = fmaf(uu[c], qB1, tpB[1][c]);
                    }
                    ++ab;
                }
            }
            #pragma unroll
            for (int n = 0; n < NB; ++n) {
                #pragma unroll
                for (int c = 0; c < 9; ++c) {
                    s_tp[n][c][tid]       = tpA[n][c];
                    s_tp[n][c][tid + 128] = tpB[n][c];
                }
            }
        }
        __syncthreads();   // tp visible to all columns

        // ---------- step 4: linear_out, 2 kk/thread (ln, ln+64), p-half per wave
        {
            const float* V0 = W_out + (size_t)(it * 3 + 0) * PCH * KCH + ln;
            const float* V1 = W_out + (size_t)(it * 3 + 1) * PCH * KCH + ln;
            const float* V2 = W_out + (size_t)(it * 3 + 2) * PCH * KCH + ln;
            const int pb0 = w * 128;   // this wave's p-half (uniform)

            float oaA[NB][9], oaB[NB][9];   // kkA = ln, kkB = ln+64
            #pragma unroll
            for (int n = 0; n < NB; ++n)
                #pragma unroll
                for (int m = 0; m < 9; ++m) { oaA[n][m] = 0.0f; oaB[n][m] = 0.0f; }

            #pragma unroll 1
            for (int pb = 0; pb < 128; pb += 4) {
                float vv[3][4][2];
                #pragma unroll
                for (int r = 0; r < 4; ++r) {
                    const size_t row = (size_t)(pb0 + pb + r) * KCH;
                    vv[0][r][0] = V0[row];      vv[0][r][1] = V0[row + 64];
                    vv[1][r][0] = V1[row];      vv[1][r][1] = V1[row + 64];
                    vv[2][r][0] = V2[row];      vv[2][r][1] = V2[row + 64];
                }
                #pragma unroll
                for (int n = 0; n < NB; ++n) {
                    #pragma unroll
                    for (int m = 0; m < 9; ++m) {
                        const int lm = (m == 0) ? 0 : ((m < 4) ? 1 : 2);
                        const float4 t4 = *(const float4*)&s_tp[n][m][pb0 + pb];
                        float a = oaA[n][m], b = oaB[n][m];
                        a = fmaf(t4.x, vv[lm][0][0], a);
                        a = fmaf(t4.y, vv[lm][1][0], a);
                        a = fmaf(t4.z, vv[lm][2][0], a);
                        a = fmaf(t4.w, vv[lm][3][0], a);
                        b = fmaf(t4.x, vv[lm][0][1], b);
                        b = fmaf(t4.y, vv[lm][1][1], b);
                        b = fmaf(t4.z, vv[lm][2][1], b);
                        b = fmaf(t4.w, vv[lm][3][1], b);
                        oaA[n][m] = a; oaB[n][m] = b;
                    }
                }
            }

            // exchange: write the NOT-owned kk's partials to s_red (aliases dead
            // s_h); wave-uniform branches, lane-consecutive addresses.
            if (w == 0) {   // owns kkA=ln; hand kkB=ln+64 partials over
                #pragma unroll
                for (int n = 0; n < NB; ++n)
                    #pragma unroll
                    for (int m = 0; m < 9; ++m)
                        s_red[n * 9 + m][ln + 64] = oaB[n][m];
            } else {        // owns kkB=ln+64; hand kkA=ln partials over
                #pragma unroll
                for (int n = 0; n < NB; ++n)
                    #pragma unroll
                    for (int m = 0; m < 9; ++m)
                        s_red[n * 9 + m][ln] = oaA[n][m];
            }
            __syncthreads();

            if (w == 0) {
                #pragma unroll
                for (int n = 0; n < NB; ++n)
                    #pragma unroll
                    for (int m = 0; m < 9; ++m)
                        f[n][m] += oaA[n][m] + s_red[n * 9 + m][ln];
            } else {
                #pragma unroll
                for (int n = 0; n < NB; ++n)
                    #pragma unroll
                    for (int m = 0; m < 9; ++m)
                        f[n][m] += oaB[n][m] + s_red[n * 9 + m][ln + 64];
            }
        }
        __syncthreads();   // s_red reads done before next iter's RMS rewrites s_h
    }

    // ---------- store packed output (N, 9, K)
    #pragma unroll
    for (int n = 0; n < NB; ++n) {
        const int ng = node0 + n;
        #pragma unroll
        for (int m = 0; m < 9; ++m)
            out[(size_t)(ng * 9 + m) * KCH + kk] = f[n][m];
    }
}

extern "C" void kernel_launch(void* const* d_in, const int* in_sizes, int n_in,
                              void* d_out, int out_size, void* d_ws, size_t ws_size,
                              hipStream_t stream) {
    const float* f0    = (const float*)d_in[0];
    const float* f1    = (const float*)d_in[1];
    const float* f2    = (const float*)d_in[2];
    const float* U     = (const float*)d_in[3];
    const float* gamma = (const float*)d_in[4];
    const float* W_in  = (const float*)d_in[5];
    const float* W_out = (const float*)d_in[6];
    float* out = (float*)d_out;

    dim3 grid(NNODES / NB);   // 50000 / 2 = 25000, exact
    dim3 block(NTHR);
    hipLaunchKernelGGL(cg_fused, grid, block, 0, stream,
                       f0, f1, f2, U, gamma, W_in, W_out, out);
}